// Round 4
// baseline (177.088 us; speedup 1.0000x reference)
//
#include <hip/hip_runtime.h>
#include <math.h>

#define BATCH 8192
#define L 100
#define EMB 16
#define NCH 384  // 4 fields * 6 pools * 16 emb channels

// ---------------- workspace layout ----------------
// pooled : float [4][BATCH][6][16]  = 12,582,912 B
// sums   : double[384]; sumsqs : double[384]
// coefA  : float [384]; coefB  : float [384]
#define POOLED_FLOATS (4 * BATCH * 96)
#define POOLED_BYTES  (POOLED_FLOATS * 4)

// pool: 16 lanes/sample = 4 phases (j, l-split) x 4 chunks (c, float4 of EMB).
// Pass 1 is a pure streaming loop (no cross-lane serial deps): gathers +
// accumulations; per-l l2 pair-partials spilled to LDS. Pass 2 finds
// first-argmax / first-argmin from LDS and re-gathers the winning rows.
// Padded tail (l >= ln) handled analytically: contributes 0 to s/ssq/att,
// exp(0)*(L-ln) to the softmax denom, and never wins argmax (l2=0, strict >)
// or argmin (maps to 9999, first real l <= 9999 wins via strict <).
__global__ __launch_bounds__(256) void pool_kernel(
    const int* __restrict__ ids_ug, const int* __restrict__ ids_urb,
    const int* __restrict__ ids_mg, const int* __restrict__ ids_mt,
    const int* __restrict__ len_ug, const int* __restrict__ len_urb,
    const int* __restrict__ len_mg, const int* __restrict__ len_mt,
    const float* __restrict__ emb_movie, const float* __restrict__ emb_tag,
    const float* __restrict__ emb_genre,
    const float* __restrict__ att_movie, const float* __restrict__ att_tag,
    const float* __restrict__ att_genre,
    float* __restrict__ pooled, double* __restrict__ sums, double* __restrict__ sumsqs)
{
    const int f = blockIdx.y;
    const int* ids; const int* lens; const float* tab; const float* atab;
    switch (f) {
        case 0: ids = ids_ug;  lens = len_ug;  tab = emb_genre; atab = att_genre; break;
        case 1: ids = ids_urb; lens = len_urb; tab = emb_movie; atab = att_movie; break;
        case 2: ids = ids_mg;  lens = len_mg;  tab = emb_genre; atab = att_genre; break;
        default:ids = ids_mt;  lens = len_mt;  tab = emb_tag;   atab = att_tag;   break;
    }
    const int tid = threadIdx.x;
    const int sub = tid >> 4;        // sample within block (0..15)
    const int e   = tid & 15;        // lane within sample
    const int j   = e >> 2;          // l-phase
    const int c   = e & 3;           // float4 chunk (dims 4c..4c+3)
    const int b   = blockIdx.x * 16 + sub;
    const int ln  = lens[b];

    const int* idrow = ids + (size_t)b * L;
    const float4* __restrict__ tab4 = (const float4*)tab;

    // 12.8 KB; reused as the stats tile after pass 2
    __shared__ float l2buf[16][100][2];

    float4 s   = make_float4(0.f, 0.f, 0.f, 0.f);
    float4 ssq = s, att = s;
    float expsum = 0.f;

    int l = j;
    for (; l + 4 < ln; l += 8) {          // 2x unrolled: two gathers in flight
        const int id0 = idrow[l];
        const int id1 = idrow[l + 4];
        const float4 v0 = tab4[(size_t)id0 * 4 + c];
        const float4 v1 = tab4[(size_t)id1 * 4 + c];
        const float aw0 = atab[id0];
        const float aw1 = atab[id1];
        float4 w0, w1;
        w0.x = v0.x * v0.x; w0.y = v0.y * v0.y; w0.z = v0.z * v0.z; w0.w = v0.w * v0.w;
        w1.x = v1.x * v1.x; w1.y = v1.y * v1.y; w1.z = v1.z * v1.z; w1.w = v1.w * v1.w;
        s.x += v0.x + v1.x; s.y += v0.y + v1.y; s.z += v0.z + v1.z; s.w += v0.w + v1.w;
        ssq.x += w0.x + w1.x; ssq.y += w0.y + w1.y;
        ssq.z += w0.z + w1.z; ssq.w += w0.w + w1.w;
        float p0 = (w0.x + w0.y) + (w0.z + w0.w);
        float p1 = (w1.x + w1.y) + (w1.z + w1.w);
        p0 += __shfl_xor(p0, 1);          // pair-sum; feeds only the LDS write
        p1 += __shfl_xor(p1, 1);
        l2buf[sub][l][c >> 1]     = p0;   // both pair lanes write same value
        l2buf[sub][l + 4][c >> 1] = p1;
        const float e0 = __expf(aw0);
        const float e1 = __expf(aw1);
        expsum += e0 + e1;
        att.x += v0.x * e0 + v1.x * e1; att.y += v0.y * e0 + v1.y * e1;
        att.z += v0.z * e0 + v1.z * e1; att.w += v0.w * e0 + v1.w * e1;
    }
    if (l < ln) {                         // tail
        const int id0 = idrow[l];
        const float4 v0 = tab4[(size_t)id0 * 4 + c];
        const float aw0 = atab[id0];
        float4 w0;
        w0.x = v0.x * v0.x; w0.y = v0.y * v0.y; w0.z = v0.z * v0.z; w0.w = v0.w * v0.w;
        s.x += v0.x; s.y += v0.y; s.z += v0.z; s.w += v0.w;
        ssq.x += w0.x; ssq.y += w0.y; ssq.z += w0.z; ssq.w += w0.w;
        float p0 = (w0.x + w0.y) + (w0.z + w0.w);
        p0 += __shfl_xor(p0, 1);
        l2buf[sub][l][c >> 1] = p0;
        const float e0 = __expf(aw0);
        expsum += e0;
        att.x += v0.x * e0; att.y += v0.y * e0; att.z += v0.z * e0; att.w += v0.w * e0;
    }
    __syncthreads();

    // ---- pass 2: first-argmax / first-argmin over l2[l], l < ln ----
    float bmx = -1e30f; int lx = 0x7fffffff;
    float bmn =  1e30f; int lm = 0x7fffffff;
    for (int q = e; q < ln; q += 16) {
        float2 t = *(float2*)&l2buf[sub][q][0];
        float l2 = t.x + t.y;
        if (l2 > bmx) { bmx = l2; lx = q; }
        float l2m = (l2 == 0.0f) ? 9999.0f : l2;
        if (l2m < bmn) { bmn = l2m; lm = q; }
    }
    #pragma unroll
    for (int m = 1; m <= 8; m <<= 1) {
        float o  = __shfl_xor(bmx, m);
        int   ol = __shfl_xor(lx, m);
        if (o > bmx || (o == bmx && ol < lx)) { bmx = o; lx = ol; }
        float on  = __shfl_xor(bmn, m);
        int   onl = __shfl_xor(lm, m);
        if (on < bmn || (on == bmn && onl < lm)) { bmn = on; lm = onl; }
    }

    // ---- phase merge (masks 4, 8 flip j-bits; c preserved) ----
    #pragma unroll
    for (int m = 4; m <= 8; m <<= 1) {
        s.x += __shfl_xor(s.x, m); s.y += __shfl_xor(s.y, m);
        s.z += __shfl_xor(s.z, m); s.w += __shfl_xor(s.w, m);
        ssq.x += __shfl_xor(ssq.x, m); ssq.y += __shfl_xor(ssq.y, m);
        ssq.z += __shfl_xor(ssq.z, m); ssq.w += __shfl_xor(ssq.w, m);
        att.x += __shfl_xor(att.x, m); att.y += __shfl_xor(att.y, m);
        att.z += __shfl_xor(att.z, m); att.w += __shfl_xor(att.w, m);
        expsum += __shfl_xor(expsum, m);
    }
    expsum += (float)(L - ln);   // analytic padded-tail exp(0) contributions

    float4 mean;
    mean.x = s.x * (1.0f / L); mean.y = s.y * (1.0f / L);
    mean.z = s.z * (1.0f / L); mean.w = s.w * (1.0f / L);
    float4 ko;
    ko.x = 0.5f * (s.x * s.x - ssq.x); ko.y = 0.5f * (s.y * s.y - ssq.y);
    ko.z = 0.5f * (s.z * s.z - ssq.z); ko.w = 0.5f * (s.w * s.w - ssq.w);
    float pk = (ko.x * ko.x + ko.y * ko.y) + (ko.z * ko.z + ko.w * ko.w);
    float kn2 = pk + __shfl_xor(pk, 1);
    kn2 += __shfl_xor(kn2, 2);
    float rn = 1.0f / fmaxf(sqrtf(kn2), 1e-12f);
    ko.x *= rn; ko.y *= rn; ko.z *= rn; ko.w *= rn;
    float ie = 1.0f / expsum;
    att.x *= ie; att.y *= ie; att.z *= ie; att.w *= ie;

    // winning-row gathers (l < ln always, so mask is 1 there)
    float4 mxv = make_float4(0.f, 0.f, 0.f, 0.f), mnv = mxv;
    if (e < 4) {
        mxv = tab4[(size_t)idrow[lx] * 4 + e];
        mnv = tab4[(size_t)idrow[lm] * 4 + e];
    }

    __syncthreads();                       // l2buf reads done; overlay tile
    float* tile = (float*)l2buf;           // [16][100] stride-100 stats tile

    if (e < 4) {                           // j == 0 lanes, c == e
        float4 pv[6] = { s, mean, mxv, mnv, ko, att };
        float4* prow = (float4*)(pooled + ((size_t)(f * BATCH + b)) * 96);
        #pragma unroll
        for (int p = 0; p < 6; ++p) {
            prow[p * 4 + e] = pv[p];
            *(float4*)&tile[sub * 100 + p * 16 + e * 4] = pv[p];
        }
    }
    __syncthreads();
    // block-level partial stats -> double atomics (96 channels for this field)
    if (tid < 96) {
        float sm = 0.f, sq = 0.f;
        #pragma unroll
        for (int s2 = 0; s2 < 16; ++s2) {
            float x = tile[s2 * 100 + tid];
            sm += x;
            sq += x * x;
        }
        atomicAdd(&sums[f * 96 + tid],   (double)sm);
        atomicAdd(&sumsqs[f * 96 + tid], (double)sq);
    }
}

__global__ __launch_bounds__(384) void coef_kernel(
    const double* __restrict__ sums, const double* __restrict__ sumsqs,
    const float* __restrict__ gamma, const float* __restrict__ beta,
    const float* __restrict__ alpha,
    float* __restrict__ coefA, float* __restrict__ coefB)
{
    int c = threadIdx.x;          // 0..383  = f*96 + p*16 + e
    if (c >= NCH) return;
    int f = c / 96;
    int p = (c % 96) >> 4;
    double mu  = sums[c]   * (1.0 / BATCH);
    double var = sumsqs[c] * (1.0 / BATCH) - mu * mu;
    float inv = (float)(1.0 / sqrt(var + 1e-5));
    float g  = gamma[c];
    float bb = beta[c];
    float amax = -1e30f;
    for (int q = 0; q < 6; ++q) amax = fmaxf(amax, alpha[f * 6 + q]);
    float wsum = 0.f;
    for (int q = 0; q < 6; ++q) wsum += __expf(alpha[f * 6 + q] - amax);
    float wp = __expf(alpha[f * 6 + p] - amax) / wsum;
    float muf = (float)mu;
    coefA[c] = wp * g * inv;
    coefB[c] = wp * (bb - g * muf * inv);
}

#define SPB 16
__global__ __launch_bounds__(256) void final_kernel(
    const int* __restrict__ uid, const int* __restrict__ mid, const int* __restrict__ yr,
    const float* __restrict__ emb_user, const float* __restrict__ emb_movie,
    const float* __restrict__ emb_year,
    const float* __restrict__ pooled,
    const float* __restrict__ coefA, const float* __restrict__ coefB,
    const float* __restrict__ W1, const float* __restrict__ b1,
    const float* __restrict__ W2, const float* __restrict__ b2,
    const float* __restrict__ W3, const float* __restrict__ b3,
    float* __restrict__ out)
{
    __shared__ float sW1[112 * 64];   // [k][j], j contiguous
    __shared__ float sW2[64 * 32];
    __shared__ float sW3[32];
    __shared__ float sb1[64];
    __shared__ float sb2[32];
    __shared__ float xt[SPB][112];
    __shared__ float h1t[SPB][64];

    const int tid = threadIdx.x;
    for (int i = tid; i < 112 * 16; i += 256)
        ((float4*)sW1)[i] = ((const float4*)W1)[i];
    for (int i = tid; i < 64 * 8; i += 256)
        ((float4*)sW2)[i] = ((const float4*)W2)[i];
    if (tid < 32) sW3[tid] = W3[tid];
    if (tid < 64) sb1[tid] = b1[tid];
    if (tid < 32) sb2[tid] = b2[tid];

    const int sub = tid >> 4;
    const int e   = tid & 15;
    const int b   = blockIdx.x * SPB + sub;

    xt[sub][e]      = emb_user [(size_t)uid[b] * EMB + e];
    xt[sub][16 + e] = emb_movie[(size_t)mid[b] * EMB + e];
    xt[sub][32 + e] = emb_year [(size_t)yr[b]  * EMB + e];

    #pragma unroll
    for (int f = 0; f < 4; ++f) {
        const float* pr = pooled + ((size_t)(f * BATCH + b)) * 96;
        float acc = 0.f;
        #pragma unroll
        for (int p = 0; p < 6; ++p) {
            int c = f * 96 + p * 16 + e;
            acc += coefA[c] * pr[p * 16 + e] + coefB[c];
        }
        xt[sub][48 + f * 16 + e] = acc;
    }
    __syncthreads();

    // h1 = relu(x @ W1 + b1): lane e computes j = 4e..4e+3 via float4
    float4 h1 = ((float4*)sb1)[e];
    for (int k = 0; k < 112; ++k) {
        float xk = xt[sub][k];
        float4 w = ((float4*)sW1)[k * 16 + e];
        h1.x += xk * w.x; h1.y += xk * w.y; h1.z += xk * w.z; h1.w += xk * w.w;
    }
    float4 h1r;
    h1r.x = fmaxf(h1.x, 0.f); h1r.y = fmaxf(h1.y, 0.f);
    h1r.z = fmaxf(h1.z, 0.f); h1r.w = fmaxf(h1.w, 0.f);
    *(float4*)&h1t[sub][e * 4] = h1r;
    __syncthreads();

    // h2 = relu(h1 @ W2 + b2): lane e computes j = 2e, 2e+1 via float2
    float2 h2 = ((float2*)sb2)[e];
    for (int k = 0; k < 64; ++k) {
        float hk = h1t[sub][k];
        float2 w = ((float2*)sW2)[k * 16 + e];
        h2.x += hk * w.x; h2.y += hk * w.y;
    }
    float part = fmaxf(h2.x, 0.f) * sW3[2 * e] + fmaxf(h2.y, 0.f) * sW3[2 * e + 1];
    part += __shfl_xor(part, 1);
    part += __shfl_xor(part, 2);
    part += __shfl_xor(part, 4);
    part += __shfl_xor(part, 8);
    if (e == 0) {
        float t = part + b3[0];
        out[b] = 1.f / (1.f + __expf(-t));
    }
}

extern "C" void kernel_launch(void* const* d_in, const int* in_sizes, int n_in,
                              void* d_out, int out_size, void* d_ws, size_t ws_size,
                              hipStream_t stream) {
    const int* uid     = (const int*)d_in[0];
    const int* mid     = (const int*)d_in[1];
    const int* yr      = (const int*)d_in[2];
    const int* ids_ug  = (const int*)d_in[3];
    const int* ids_urb = (const int*)d_in[4];
    const int* ids_mg  = (const int*)d_in[5];
    const int* ids_mt  = (const int*)d_in[6];
    const int* len_ug  = (const int*)d_in[7];
    const int* len_urb = (const int*)d_in[8];
    const int* len_mg  = (const int*)d_in[9];
    const int* len_mt  = (const int*)d_in[10];
    const float* emb_user  = (const float*)d_in[11];
    const float* emb_movie = (const float*)d_in[12];
    const float* emb_tag   = (const float*)d_in[13];
    const float* emb_genre = (const float*)d_in[14];
    const float* emb_year  = (const float*)d_in[15];
    const float* att_movie = (const float*)d_in[16];
    const float* att_tag   = (const float*)d_in[17];
    const float* att_genre = (const float*)d_in[18];
    const float* bn_gamma  = (const float*)d_in[19];
    const float* bn_beta   = (const float*)d_in[20];
    const float* alpha     = (const float*)d_in[21];
    const float* W1 = (const float*)d_in[22];
    const float* b1 = (const float*)d_in[23];
    const float* W2 = (const float*)d_in[24];
    const float* b2 = (const float*)d_in[25];
    const float* W3 = (const float*)d_in[26];
    const float* b3 = (const float*)d_in[27];
    float* out = (float*)d_out;

    float*  pooled = (float*)d_ws;
    double* sums   = (double*)((char*)d_ws + POOLED_BYTES);
    double* sumsqs = sums + NCH;
    float*  coefA  = (float*)(sums + 2 * NCH);
    float*  coefB  = coefA + NCH;

    hipMemsetAsync(sums, 0, 2 * NCH * sizeof(double), stream);
    pool_kernel<<<dim3(BATCH / 16, 4), 256, 0, stream>>>(
        ids_ug, ids_urb, ids_mg, ids_mt,
        len_ug, len_urb, len_mg, len_mt,
        emb_movie, emb_tag, emb_genre,
        att_movie, att_tag, att_genre,
        pooled, sums, sumsqs);
    coef_kernel<<<1, 384, 0, stream>>>(sums, sumsqs, bn_gamma, bn_beta, alpha,
                                       coefA, coefB);
    final_kernel<<<BATCH / SPB, 256, 0, stream>>>(
        uid, mid, yr, emb_user, emb_movie, emb_year,
        pooled, coefA, coefB, W1, b1, W2, b2, W3, b3, out);
}